// Round 1
// baseline (294.233 us; speedup 1.0000x reference)
//
#include <hip/hip_runtime.h>

#define NF_   2
#define NLOC_ 2048
#define NALL_ 3072
#define NNEI_ 128
#define H_    8
#define D_    32
#define CH_   256   // H*D == Q_DIM

// ---------------------------------------------------------------------------
// Generic fp32 GEMM tile: C[M,256] = A[M,256] @ W[256,256]^T (+ epilogue)
// BM=128, BN=64, BK=16, 256 threads, 8x4 micro-tile per thread.
// mode: 0 = *norm (qh), 1 = sigmoid(x + bvec[col]) (gate), 2 = none, 3 = +bvec[col]
// ---------------------------------------------------------------------------
__device__ __forceinline__ void gemm128x64(
    const float* __restrict__ A, const float* __restrict__ W,
    const float* __restrict__ bvec, float* __restrict__ C,
    int M, int mode, float (*As)[132], float (*Bs)[68]) {
  const int t  = threadIdx.x;
  const int m0 = blockIdx.y * 128;
  if (m0 >= M) return;
  const int n0 = blockIdx.x * 64;
  const int tx = t & 15;        // 16 col-groups of 4
  const int ty = t >> 4;        // 16 row-groups of 8

  float acc[8][4] = {};

  const int arow = t >> 1;          // 0..127
  const int ak   = (t & 1) * 8;     // 0 or 8
  const int wrow = t >> 2;          // 0..63
  const int wk   = (t & 3) * 4;     // 0,4,8,12

  for (int k0 = 0; k0 < 256; k0 += 16) {
    const float4 a0 = *(const float4*)(A + (size_t)(m0 + arow) * 256 + k0 + ak);
    const float4 a1 = *(const float4*)(A + (size_t)(m0 + arow) * 256 + k0 + ak + 4);
    const float4 w0 = *(const float4*)(W + (size_t)(n0 + wrow) * 256 + k0 + wk);
    As[ak + 0][arow] = a0.x; As[ak + 1][arow] = a0.y;
    As[ak + 2][arow] = a0.z; As[ak + 3][arow] = a0.w;
    As[ak + 4][arow] = a1.x; As[ak + 5][arow] = a1.y;
    As[ak + 6][arow] = a1.z; As[ak + 7][arow] = a1.w;
    Bs[wk + 0][wrow] = w0.x; Bs[wk + 1][wrow] = w0.y;
    Bs[wk + 2][wrow] = w0.z; Bs[wk + 3][wrow] = w0.w;
    __syncthreads();
#pragma unroll
    for (int kk = 0; kk < 16; ++kk) {
      const float4 av0 = *(const float4*)(&As[kk][ty * 8]);
      const float4 av1 = *(const float4*)(&As[kk][ty * 8 + 4]);
      const float4 bv  = *(const float4*)(&Bs[kk][tx * 4]);
      const float a[8] = {av0.x, av0.y, av0.z, av0.w, av1.x, av1.y, av1.z, av1.w};
      const float b[4] = {bv.x, bv.y, bv.z, bv.w};
#pragma unroll
      for (int i = 0; i < 8; ++i)
#pragma unroll
        for (int j = 0; j < 4; ++j) acc[i][j] = fmaf(a[i], b[j], acc[i][j]);
    }
    __syncthreads();
  }

  const float norm = 0.17677669529663687f;  // 1/sqrt(32)
#pragma unroll
  for (int i = 0; i < 8; ++i) {
    const int row = m0 + ty * 8 + i;
    float4 o;
    float* op = (float*)&o;
#pragma unroll
    for (int j = 0; j < 4; ++j) {
      const int col = n0 + tx * 4 + j;
      float v = acc[i][j];
      if (mode == 0)      v *= norm;
      else if (mode == 1) v = 1.f / (1.f + __expf(-(v + bvec[col])));
      else if (mode == 3) v += bvec[col];
      op[j] = v;
    }
    *(float4*)(C + (size_t)row * 256 + n0 + tx * 4) = o;
  }
}

__global__ __launch_bounds__(256) void proj_kernel(
    const float* __restrict__ q, const float* __restrict__ k, const float* __restrict__ v,
    const float* __restrict__ Wq, const float* __restrict__ Wg,
    const float* __restrict__ Wk, const float* __restrict__ Wv,
    const float* __restrict__ bg,
    float* __restrict__ qh, float* __restrict__ gs,
    float* __restrict__ kh, float* __restrict__ vh) {
  __shared__ float As[16][132];
  __shared__ float Bs[16][68];
  switch (blockIdx.z) {
    case 0:  gemm128x64(q, Wq, nullptr, qh, NF_ * NLOC_, 0, As, Bs); break;
    case 1:  gemm128x64(q, Wg, bg,      gs, NF_ * NLOC_, 1, As, Bs); break;
    case 2:  gemm128x64(k, Wk, nullptr, kh, NF_ * NALL_, 2, As, Bs); break;
    default: gemm128x64(v, Wv, nullptr, vh, NF_ * NALL_, 2, As, Bs); break;
  }
}

__global__ __launch_bounds__(256) void out_gemm_kernel(
    const float* __restrict__ x, const float* __restrict__ Wo,
    const float* __restrict__ bo, float* __restrict__ out) {
  __shared__ float As[16][132];
  __shared__ float Bs[16][68];
  gemm128x64(x, Wo, bo, out, NF_ * NLOC_, 3, As, Bs);
}

// ---------------------------------------------------------------------------
// Attention: one block per (f, n) atom. 256 threads.
//   phase 1: load q row + nlist (runtime int32/int64 detect)
//   phase 2: scores  (thread t -> head h=t>>5, lane il=t&31; 4 neighbors each)
//   phase 3: softmax via shfl within 32-lane head groups
//   phase 4: PV (thread t -> (h, d)); gate with sigmoid(g); write x
// ---------------------------------------------------------------------------
__global__ __launch_bounds__(256) void attn_kernel(
    const float* __restrict__ qh, const float* __restrict__ gs,
    const float* __restrict__ kh, const float* __restrict__ vh,
    const void* __restrict__ nlist, const float* __restrict__ bias,
    float* __restrict__ x) {
  __shared__ float q_s[CH_];
  __shared__ int   jn[NNEI_];
  __shared__ float p[H_][NNEI_ + 4];  // pad: head stride 132 -> banks (4h+i)%32

  const int t   = threadIdx.x;
  const int bid = blockIdx.x;        // == f*NLOC + n
  const int f   = bid >> 11;
  const int n   = bid & (NLOC_ - 1);
  const size_t row = (size_t)bid;

  q_s[t] = qh[row * CH_ + t];

  // nlist dtype detection: int64 -> all high 32-bit words are 0
  const int* nl32 = (const int*)nlist;
  int odd_or = 0;
#pragma unroll
  for (int w = 1; w < 16; w += 2) odd_or |= nl32[w];
  if (t < NNEI_) {
    if (odd_or == 0) {
      const long long* nl64 = (const long long*)nlist;
      jn[t] = (int)nl64[row * NNEI_ + t];
    } else {
      jn[t] = nl32[row * NNEI_ + t];
    }
  }
  __syncthreads();

  const int h  = t >> 5;
  const int il = t & 31;

  // hoist q fragment for this head into registers
  float4 qv[8];
  const float4* qp = (const float4*)(q_s + h * D_);
#pragma unroll
  for (int i = 0; i < 8; ++i) qv[i] = qp[i];

  const float* kbase = kh + (size_t)f * NALL_ * CH_ + h * D_;
  const float* bb    = bias + (((size_t)f * H_ + h) * NLOC_ + n) * NNEI_;

  float s[4];
#pragma unroll
  for (int r = 0; r < 4; ++r) {
    const int i = il + 32 * r;
    const int j = jn[i];
    const float4* kr = (const float4*)(kbase + (size_t)j * CH_);
    float a = 0.f;
#pragma unroll
    for (int d4 = 0; d4 < 8; ++d4) {
      const float4 kv = kr[d4];
      a = fmaf(qv[d4].x, kv.x, a);
      a = fmaf(qv[d4].y, kv.y, a);
      a = fmaf(qv[d4].z, kv.z, a);
      a = fmaf(qv[d4].w, kv.w, a);
    }
    s[r] = a + bb[i];
  }

  // softmax over 128 values (4 regs x 32 lanes of this head group)
  float m = fmaxf(fmaxf(s[0], s[1]), fmaxf(s[2], s[3]));
#pragma unroll
  for (int off = 16; off >= 1; off >>= 1) m = fmaxf(m, __shfl_xor(m, off));
  float e[4];
  float sum = 0.f;
#pragma unroll
  for (int r = 0; r < 4; ++r) { e[r] = __expf(s[r] - m); sum += e[r]; }
#pragma unroll
  for (int off = 16; off >= 1; off >>= 1) sum += __shfl_xor(sum, off);
  const float inv = 1.f / sum;
#pragma unroll
  for (int r = 0; r < 4; ++r) p[h][il + 32 * r] = e[r] * inv;
  __syncthreads();

  // PV: thread t -> (h, d). For fixed i, 32 lanes read 128B contiguous of vh row.
  const int d = il;
  const float* vb = vh + (size_t)f * NALL_ * CH_ + h * D_ + d;
  float acc = 0.f;
  for (int i = 0; i < NNEI_; i += 4) {
    const float4 p4 = *(const float4*)(&p[h][i]);
    const int4  j4 = *(const int4*)(&jn[i]);
    acc = fmaf(p4.x, vb[(size_t)j4.x * CH_], acc);
    acc = fmaf(p4.y, vb[(size_t)j4.y * CH_], acc);
    acc = fmaf(p4.z, vb[(size_t)j4.z * CH_], acc);
    acc = fmaf(p4.w, vb[(size_t)j4.w * CH_], acc);
  }

  const float g = gs[row * CH_ + t];
  x[row * CH_ + t] = g * acc;
}

// ---------------------------------------------------------------------------
extern "C" void kernel_launch(void* const* d_in, const int* in_sizes, int n_in,
                              void* d_out, int out_size, void* d_ws, size_t ws_size,
                              hipStream_t stream) {
  const float* q     = (const float*)d_in[0];
  const float* k     = (const float*)d_in[1];
  const float* v     = (const float*)d_in[2];
  const void*  nlist = d_in[3];
  const float* bias  = (const float*)d_in[4];
  const float* Wq    = (const float*)d_in[5];
  const float* Wk    = (const float*)d_in[6];
  const float* Wv    = (const float*)d_in[7];
  const float* Wg    = (const float*)d_in[8];
  const float* bg    = (const float*)d_in[9];
  const float* Wo    = (const float*)d_in[10];
  const float* bo    = (const float*)d_in[11];
  float* out = (float*)d_out;

  float* ws = (float*)d_ws;
  float* qh = ws;                                   // [4096,256]
  float* gs = qh + (size_t)NF_ * NLOC_ * CH_;       // [4096,256]
  float* kh = gs + (size_t)NF_ * NLOC_ * CH_;       // [6144,256]
  float* vh = kh + (size_t)NF_ * NALL_ * CH_;       // [6144,256]
  float* x  = vh + (size_t)NF_ * NALL_ * CH_;       // [4096,256]

  // projections: z = {qh, gate, kh, vh}
  proj_kernel<<<dim3(4, 48, 4), 256, 0, stream>>>(q, k, v, Wq, Wg, Wk, Wv, bg,
                                                  qh, gs, kh, vh);
  // attention + gating
  attn_kernel<<<dim3(NF_ * NLOC_), 256, 0, stream>>>(qh, gs, kh, vh, nlist, bias, x);
  // output projection
  out_gemm_kernel<<<dim3(4, 32), 256, 0, stream>>>(x, Wo, bo, out);
}